// Round 3
// baseline (280.780 us; speedup 1.0000x reference)
//
#include <hip/hip_runtime.h>
#include <hip/hip_bf16.h>
#include <cstdint>

typedef __bf16 bf16;
typedef bf16 bf16x4 __attribute__((ext_vector_type(4)));
typedef bf16 bf16x8 __attribute__((ext_vector_type(8)));
typedef float f32x4 __attribute__((ext_vector_type(4)));

#define MFMA16(a, b, c) __builtin_amdgcn_mfma_f32_16x16x32_bf16((a), (b), (c), 0, 0, 0)

// async global->LDS DMA, 16B/lane. LDS dest must be wave-uniform base + lane*16.
__device__ inline void async16(const bf16* g, bf16* l) {
  __builtin_amdgcn_global_load_lds(
      (const __attribute__((address_space(1))) void*)g,
      (__attribute__((address_space(3))) void*)l, 16, 0, 0);
}

// workgroup barrier that drains ONLY lgkm (LDS) — leaves global prefetch in flight
__device__ inline void lds_barrier() {
  asm volatile("s_waitcnt lgkmcnt(0)\n\ts_barrier" ::: "memory");
}

// ------------------------------------------------------------------
// cast fp32 -> bf16, 4 elems/thread
// ------------------------------------------------------------------
__global__ void cast_f32_to_bf16(const float* __restrict__ src,
                                 bf16* __restrict__ dst, int n4) {
  int i = blockIdx.x * blockDim.x + threadIdx.x;
  if (i < n4) {
    const float4 v = ((const float4*)src)[i];
    bf16x4 o;
    o.x = (bf16)v.x; o.y = (bf16)v.y; o.z = (bf16)v.z; o.w = (bf16)v.w;
    ((bf16x4*)dst)[i] = o;
  }
}

// ------------------------------------------------------------------
// GEMM1: C[m,e] = sum_c x[m,c] * W1[e,c]   (M=8192, N=1536, K=1024)
// global_load_lds staging, xor-swizzled unpadded LDS (stride 64).
// Element A[m0+row][k0+kc*8+e] lives at sA[row*64 + (kc^(row&7))*8 + e].
// ------------------------------------------------------------------
__global__ __launch_bounds__(256, 2)
void gemm_qkv(const bf16* __restrict__ A, const bf16* __restrict__ B,
              bf16* __restrict__ qb, bf16* __restrict__ kb, bf16* __restrict__ vb) {
  constexpr int K = 1024;
  __shared__ bf16 sA[128 * 64];
  __shared__ bf16 sB[128 * 64];
  const int tid = threadIdx.x;
  const int lane = tid & 63, wid = tid >> 6;
  const int col = lane & 15, quad = lane >> 4;
  const int wm = wid >> 1, wn = wid & 1;
  const int m0 = blockIdx.y * 128, n0 = blockIdx.x * 128;
  const int c7 = col & 7;

  f32x4 acc[4][4];
  const f32x4 z = {0.f, 0.f, 0.f, 0.f};
#pragma unroll
  for (int mi = 0; mi < 4; mi++)
#pragma unroll
    for (int ni = 0; ni < 4; ni++) acc[mi][ni] = z;

  for (int k0 = 0; k0 < K; k0 += 64) {
    __syncthreads();
#pragma unroll
    for (int c = 0; c < 4; ++c) {
      const int idx = c * 256 + tid;
      const int row = idx >> 3, kc = idx & 7;
      const int gkc = kc ^ (row & 7);
      async16(&A[(size_t)(m0 + row) * K + k0 + gkc * 8], &sA[idx * 8]);
      async16(&B[(size_t)(n0 + row) * K + k0 + gkc * 8], &sB[idx * 8]);
    }
    __syncthreads();  // vmcnt(0) drain: DMA complete
#pragma unroll
    for (int ks = 0; ks < 2; ++ks) {
      bf16x8 af[4], bfr[4];
#pragma unroll
      for (int i = 0; i < 4; i++)
        af[i] = *(const bf16x8*)&sA[(wm * 64 + i * 16 + col) * 64 +
                                    (((ks * 4 + quad) ^ c7) << 3)];
#pragma unroll
      for (int i = 0; i < 4; i++)
        bfr[i] = *(const bf16x8*)&sB[(wn * 64 + i * 16 + col) * 64 +
                                     (((ks * 4 + quad) ^ c7) << 3)];
#pragma unroll
      for (int mi = 0; mi < 4; mi++)
#pragma unroll
        for (int ni = 0; ni < 4; ni++)
          acc[mi][ni] = MFMA16(af[mi], bfr[ni], acc[mi][ni]);
    }
  }
#pragma unroll
  for (int mi = 0; mi < 4; mi++) {
#pragma unroll
    for (int ni = 0; ni < 4; ni++) {
      const int e = n0 + wn * 64 + ni * 16 + col;
#pragma unroll
      for (int r = 0; r < 4; r++) {
        const int m = m0 + wm * 64 + mi * 16 + quad * 4 + r;
        const int bb = m >> 11, t = m & 2047;
        const bf16 val = (bf16)acc[mi][ni][r];
        if (e < 1024) {
          qb[(((size_t)bb * 16 + (e >> 6)) * 2048 + t) * 64 + (e & 63)] = val;
        } else if (e < 1280) {
          const int f = e - 1024;
          kb[(((size_t)bb * 4 + (f >> 6)) * 2048 + t) * 64 + (f & 63)] = val;
        } else {
          const int f = e - 1280;
          vb[(((size_t)bb * 4 + (f >> 6)) * 2048 + t) * 64 + (f & 63)] = val;
        }
      }
    }
  }
}

// ------------------------------------------------------------------
// GEMM2: out[m,e] = sum_c AO[m,c] * Wproj[e,c] + bias[e]  (fp32 out)
// ------------------------------------------------------------------
__global__ __launch_bounds__(256, 2)
void gemm_proj(const bf16* __restrict__ A, const bf16* __restrict__ B,
               const float* __restrict__ bias, float* __restrict__ out) {
  constexpr int K = 1024;
  __shared__ bf16 sA[128 * 64];
  __shared__ bf16 sB[128 * 64];
  const int tid = threadIdx.x;
  const int lane = tid & 63, wid = tid >> 6;
  const int col = lane & 15, quad = lane >> 4;
  const int wm = wid >> 1, wn = wid & 1;
  const int m0 = blockIdx.y * 128, n0 = blockIdx.x * 128;
  const int c7 = col & 7;

  f32x4 acc[4][4];
  const f32x4 z = {0.f, 0.f, 0.f, 0.f};
#pragma unroll
  for (int mi = 0; mi < 4; mi++)
#pragma unroll
    for (int ni = 0; ni < 4; ni++) acc[mi][ni] = z;

  for (int k0 = 0; k0 < K; k0 += 64) {
    __syncthreads();
#pragma unroll
    for (int c = 0; c < 4; ++c) {
      const int idx = c * 256 + tid;
      const int row = idx >> 3, kc = idx & 7;
      const int gkc = kc ^ (row & 7);
      async16(&A[(size_t)(m0 + row) * K + k0 + gkc * 8], &sA[idx * 8]);
      async16(&B[(size_t)(n0 + row) * K + k0 + gkc * 8], &sB[idx * 8]);
    }
    __syncthreads();
#pragma unroll
    for (int ks = 0; ks < 2; ++ks) {
      bf16x8 af[4], bfr[4];
#pragma unroll
      for (int i = 0; i < 4; i++)
        af[i] = *(const bf16x8*)&sA[(wm * 64 + i * 16 + col) * 64 +
                                    (((ks * 4 + quad) ^ c7) << 3)];
#pragma unroll
      for (int i = 0; i < 4; i++)
        bfr[i] = *(const bf16x8*)&sB[(wn * 64 + i * 16 + col) * 64 +
                                     (((ks * 4 + quad) ^ c7) << 3)];
#pragma unroll
      for (int mi = 0; mi < 4; mi++)
#pragma unroll
        for (int ni = 0; ni < 4; ni++)
          acc[mi][ni] = MFMA16(af[mi], bfr[ni], acc[mi][ni]);
    }
  }
#pragma unroll
  for (int mi = 0; mi < 4; mi++) {
#pragma unroll
    for (int ni = 0; ni < 4; ni++) {
      const int e = n0 + wn * 64 + ni * 16 + col;
      const float be = bias[e];
#pragma unroll
      for (int r = 0; r < 4; r++) {
        const int m = m0 + wm * 64 + mi * 16 + quad * 4 + r;
        out[(size_t)m * 1024 + e] = acc[mi][ni][r] + be;
      }
    }
  }
}

// ------------------------------------------------------------------
// Flash attention, ALiBi bias, fixed-max softmax, transposed dataflow.
// NEW: K/V register-prefetch pipeline + lgkm-only barriers so global
// loads for chunk c+1 stay in flight across the whole compute of c.
// ------------------------------------------------------------------
__global__ __launch_bounds__(256, 2)
void attn_alibi(const bf16* __restrict__ qb, const bf16* __restrict__ kb,
                const bf16* __restrict__ vb, bf16* __restrict__ ob) {
  __shared__ bf16 sK[64 * 72];      // [kv][d], stride 72
  __shared__ bf16 sVt[64 * 72];     // [d][kv], kv-block xor-swizzled by d>>3
  __shared__ bf16 sPt[4][64 * 72];  // per wave: [q][kv]
  __shared__ float sL[4][64];
  const int tid = threadIdx.x;
  const int lane = tid & 63, wid = tid >> 6;
  const int col = lane & 15, quad = lane >> 4;
  const int bh = blockIdx.y;
  const int b = bh >> 4, h = bh & 15, kvh = h & 3;
  const int qbase = __builtin_amdgcn_readfirstlane(blockIdx.x * 256 + wid * 64);

  const bf16* qptr = qb + ((size_t)(b * 16 + h) * 2048 + qbase) * 64;
  const bf16* kptr = kb + ((size_t)(b * 4 + kvh) * 2048) * 64;
  const bf16* vptr = vb + ((size_t)(b * 4 + kvh) * 2048) * 64;

  // Q resident as B-operand frags: B[n=q (col)][k=d]
  bf16x8 bq[4][2];
#pragma unroll
  for (int ni = 0; ni < 4; ni++)
#pragma unroll
    for (int ks = 0; ks < 2; ks++)
      bq[ni][ks] = *(const bf16x8*)&qptr[(ni * 16 + col) * 64 + ks * 32 + quad * 8];

  f32x4 O[4][4];
  const f32x4 z = {0.f, 0.f, 0.f, 0.f};
#pragma unroll
  for (int mi = 0; mi < 4; mi++)
#pragma unroll
    for (int nd = 0; nd < 4; nd++) O[mi][nd] = z;
  float lsum[4] = {0.f, 0.f, 0.f, 0.f};

  const float c1 = 0.125f * 1.44269504f;
  const float cb = exp2f(-0.5f * (float)(h + 1)) * c1;
  const int qoff = quad * 4 - col;

  // staging coordinates for this thread (2 rows of 8 bf16 for K and V each)
  const int r0 = tid >> 3, r1 = 32 + (tid >> 3), kc = tid & 7;

  // prefetch chunk 0
  bf16x8 kr0, kr1, vr0, vr1;
  kr0 = *(const bf16x8*)&kptr[(size_t)r0 * 64 + kc * 8];
  kr1 = *(const bf16x8*)&kptr[(size_t)r1 * 64 + kc * 8];
  vr0 = *(const bf16x8*)&vptr[(size_t)r0 * 64 + kc * 8];
  vr1 = *(const bf16x8*)&vptr[(size_t)r1 * 64 + kc * 8];

  for (int c0 = 0; c0 < 2048; c0 += 64) {
    lds_barrier();  // all waves done reading previous chunk's sK/sVt
    // commit prefetched regs to LDS
    *(bf16x8*)&sK[r0 * 72 + kc * 8] = kr0;
    *(bf16x8*)&sK[r1 * 72 + kc * 8] = kr1;
    {
      const int blk0 = r0 >> 3, rl0 = r0 & 7;
      const int blk1 = r1 >> 3, rl1 = r1 & 7;
#pragma unroll
      for (int j = 0; j < 8; j++) {
        sVt[(kc * 8 + j) * 72 + ((blk0 ^ kc) << 3) + rl0] = vr0[j];
        sVt[(kc * 8 + j) * 72 + ((blk1 ^ kc) << 3) + rl1] = vr1[j];
      }
    }
    // issue next chunk's loads (WAR on kr/vr orders these after the writes)
    {
      const int cn = (c0 + 64 < 2048) ? c0 + 64 : 0;
      kr0 = *(const bf16x8*)&kptr[(size_t)(cn + r0) * 64 + kc * 8];
      kr1 = *(const bf16x8*)&kptr[(size_t)(cn + r1) * 64 + kc * 8];
      vr0 = *(const bf16x8*)&vptr[(size_t)(cn + r0) * 64 + kc * 8];
      vr1 = *(const bf16x8*)&vptr[(size_t)(cn + r1) * 64 + kc * 8];
    }
    lds_barrier();  // staging visible; prefetch loads remain in flight

    // S^T = K Q^T
    f32x4 S[4][4];
#pragma unroll
    for (int mi = 0; mi < 4; mi++)
#pragma unroll
      for (int ni = 0; ni < 4; ni++) S[mi][ni] = z;
#pragma unroll
    for (int ks = 0; ks < 2; ks++) {
      bf16x8 ak[4];
#pragma unroll
      for (int mi = 0; mi < 4; mi++)
        ak[mi] = *(const bf16x8*)&sK[(mi * 16 + col) * 72 + ks * 32 + quad * 8];
#pragma unroll
      for (int mi = 0; mi < 4; mi++)
#pragma unroll
        for (int ni = 0; ni < 4; ni++)
          S[mi][ni] = MFMA16(ak[mi], bq[ni][ks], S[mi][ni]);
    }

    // bias + exp2 (fixed max), in-lane partial row sums, pack P
    bf16* sp = sPt[wid];
#pragma unroll
    for (int ni = 0; ni < 4; ni++) {
      f32x4 p[4];
#pragma unroll
      for (int mi = 0; mi < 4; mi++) {
        const int U = c0 + mi * 16 - qbase - ni * 16;  // wave-uniform
        if (U <= -15) {
          const float bb = cb * (float)(U + qoff);
#pragma unroll
          for (int r = 0; r < 4; r++)
            p[mi][r] = __builtin_amdgcn_exp2f(S[mi][ni][r] * c1 + (bb + cb * (float)r));
        } else if (U >= 16) {
#pragma unroll
          for (int r = 0; r < 4; r++)
            p[mi][r] = __builtin_amdgcn_exp2f(S[mi][ni][r] * c1);
        } else {
          const float relf = (float)(U + qoff);
#pragma unroll
          for (int r = 0; r < 4; r++) {
            const float rr = relf + (float)r;
            const float bb = (rr <= 0.f) ? cb * rr : 0.f;
            p[mi][r] = __builtin_amdgcn_exp2f(S[mi][ni][r] * c1 + bb);
          }
        }
      }
      f32x4 t = (p[0] + p[1]) + (p[2] + p[3]);
      lsum[ni] += (t.x + t.y) + (t.z + t.w);
#pragma unroll
      for (int mi = 0; mi < 4; mi++) {
        bf16x4 w;
#pragma unroll
        for (int r = 0; r < 4; r++) w[r] = (bf16)p[mi][r];
        *(bf16x4*)&sp[(ni * 16 + col) * 72 + mi * 16 + quad * 4] = w;
      }
    }

    // O += P V   (same-wave sPt dependency handled by lgkmcnt)
#pragma unroll
    for (int ks = 0; ks < 2; ks++) {
      bf16x8 ap[4], bv[4];
#pragma unroll
      for (int mi = 0; mi < 4; mi++)
        ap[mi] = *(const bf16x8*)&sp[(mi * 16 + col) * 72 + ks * 32 + quad * 8];
#pragma unroll
      for (int nd = 0; nd < 4; nd++) {
        const int d = nd * 16 + col;
        bv[nd] = *(const bf16x8*)&sVt[d * 72 + (((ks * 4 + quad) ^ (d >> 3)) << 3)];
      }
#pragma unroll
      for (int mi = 0; mi < 4; mi++)
#pragma unroll
        for (int nd = 0; nd < 4; nd++)
          O[mi][nd] = MFMA16(ap[mi], bv[nd], O[mi][nd]);
    }
  }

  // finish row sums: cross-quad reduce, transpose via LDS
#pragma unroll
  for (int ni = 0; ni < 4; ni++) {
    float l = lsum[ni];
    l += __shfl_xor(l, 16);
    l += __shfl_xor(l, 32);
    lsum[ni] = l;
  }
  __syncthreads();
  if (quad == 0) {
#pragma unroll
    for (int ni = 0; ni < 4; ni++) sL[wid][ni * 16 + col] = lsum[ni];
  }
  __syncthreads();

#pragma unroll
  for (int mi = 0; mi < 4; mi++) {
    const f32x4 lv = *(const f32x4*)&sL[wid][mi * 16 + quad * 4];
#pragma unroll
    for (int r = 0; r < 4; r++) {
      const float inv = 1.0f / lv[r];
      const int t = qbase + mi * 16 + quad * 4 + r;
#pragma unroll
      for (int nd = 0; nd < 4; nd++) {
        ob[((size_t)b * 2048 + t) * 1024 + h * 64 + nd * 16 + col] =
            (bf16)(O[mi][nd][r] * inv);
      }
    }
  }
}

// ------------------------------------------------------------------
extern "C" void kernel_launch(void* const* d_in, const int* in_sizes, int n_in,
                              void* d_out, int out_size, void* d_ws, size_t ws_size,
                              hipStream_t stream) {
  const float* x     = (const float*)d_in[0];
  const float* Wq    = (const float*)d_in[1];
  const float* Wkv   = (const float*)d_in[2];
  const float* Wproj = (const float*)d_in[3];
  const float* bproj = (const float*)d_in[4];
  float* out = (float*)d_out;

  bf16* xb  = (bf16*)d_ws;            // 8192*1024
  bf16* w1b = xb  + 8388608;          // 1536*1024
  bf16* wpb = w1b + 1572864;          // 1024*1024
  bf16* qb  = wpb + 1048576;          // [4,16,2048,64]
  bf16* kb  = qb  + 8388608;          // [4,4,2048,64]
  bf16* vb  = kb  + 2097152;          // [4,4,2048,64]
  bf16* aob = vb  + 2097152;          // [4,2048,1024]

  cast_f32_to_bf16<<<8192, 256, 0, stream>>>(x, xb, 2097152);
  cast_f32_to_bf16<<<1024, 256, 0, stream>>>(Wq, w1b, 262144);
  cast_f32_to_bf16<<<512, 256, 0, stream>>>(Wkv, w1b + 1048576, 131072);
  cast_f32_to_bf16<<<1024, 256, 0, stream>>>(Wproj, wpb, 262144);

  gemm_qkv<<<dim3(12, 64), 256, 0, stream>>>(xb, w1b, qb, kb, vb);
  attn_alibi<<<dim3(8, 64), 256, 0, stream>>>(qb, kb, vb, aob);
  gemm_proj<<<dim3(8, 64), 256, 0, stream>>>(aob, wpb, bproj, out);
}

// Round 4
// 248.528 us; speedup vs baseline: 1.1298x; 1.1298x over previous
//
#include <hip/hip_runtime.h>
#include <hip/hip_bf16.h>
#include <cstdint>

typedef __bf16 bf16;
typedef bf16 bf16x2 __attribute__((ext_vector_type(2)));
typedef bf16 bf16x4 __attribute__((ext_vector_type(4)));
typedef bf16 bf16x8 __attribute__((ext_vector_type(8)));
typedef float f32x4 __attribute__((ext_vector_type(4)));

#define MFMA16(a, b, c) __builtin_amdgcn_mfma_f32_16x16x32_bf16((a), (b), (c), 0, 0, 0)

// 0.125 * log2(e): folded into Q at the QKV-GEMM epilogue
#define QSCALE 0.18033688011112042f

// async global->LDS DMA, 16B/lane. LDS dest must be wave-uniform base + lane*16.
__device__ inline void async16(const bf16* g, bf16* l) {
  __builtin_amdgcn_global_load_lds(
      (const __attribute__((address_space(1))) void*)g,
      (__attribute__((address_space(3))) void*)l, 16, 0, 0);
}

// ------------------------------------------------------------------
// cast fp32 -> bf16, 4 elems/thread
// ------------------------------------------------------------------
__global__ void cast_f32_to_bf16(const float* __restrict__ src,
                                 bf16* __restrict__ dst, int n4) {
  int i = blockIdx.x * blockDim.x + threadIdx.x;
  if (i < n4) {
    const float4 v = ((const float4*)src)[i];
    bf16x4 o;
    o.x = (bf16)v.x; o.y = (bf16)v.y; o.z = (bf16)v.z; o.w = (bf16)v.w;
    ((bf16x4*)dst)[i] = o;
  }
}

// ------------------------------------------------------------------
// GEMM1: C[m,e] = sum_c x[m,c] * W1[e,c]   (M=8192, N=1536, K=1024)
// global_load_lds staging, xor-swizzled unpadded LDS (stride 64).
// Q outputs pre-scaled by QSCALE for the attention exp2 domain.
// ------------------------------------------------------------------
__global__ __launch_bounds__(256, 2)
void gemm_qkv(const bf16* __restrict__ A, const bf16* __restrict__ B,
              bf16* __restrict__ qb, bf16* __restrict__ kb, bf16* __restrict__ vb) {
  constexpr int K = 1024;
  __shared__ bf16 sA[128 * 64];
  __shared__ bf16 sB[128 * 64];
  const int tid = threadIdx.x;
  const int lane = tid & 63, wid = tid >> 6;
  const int col = lane & 15, quad = lane >> 4;
  const int wm = wid >> 1, wn = wid & 1;
  const int m0 = blockIdx.y * 128, n0 = blockIdx.x * 128;
  const int c7 = col & 7;

  f32x4 acc[4][4];
  const f32x4 z = {0.f, 0.f, 0.f, 0.f};
#pragma unroll
  for (int mi = 0; mi < 4; mi++)
#pragma unroll
    for (int ni = 0; ni < 4; ni++) acc[mi][ni] = z;

  for (int k0 = 0; k0 < K; k0 += 64) {
    __syncthreads();
#pragma unroll
    for (int c = 0; c < 4; ++c) {
      const int idx = c * 256 + tid;
      const int row = idx >> 3, kc = idx & 7;
      const int gkc = kc ^ (row & 7);
      async16(&A[(size_t)(m0 + row) * K + k0 + gkc * 8], &sA[idx * 8]);
      async16(&B[(size_t)(n0 + row) * K + k0 + gkc * 8], &sB[idx * 8]);
    }
    __syncthreads();  // vmcnt(0) drain: DMA complete
#pragma unroll
    for (int ks = 0; ks < 2; ++ks) {
      bf16x8 af[4], bfr[4];
#pragma unroll
      for (int i = 0; i < 4; i++)
        af[i] = *(const bf16x8*)&sA[(wm * 64 + i * 16 + col) * 64 +
                                    (((ks * 4 + quad) ^ c7) << 3)];
#pragma unroll
      for (int i = 0; i < 4; i++)
        bfr[i] = *(const bf16x8*)&sB[(wn * 64 + i * 16 + col) * 64 +
                                     (((ks * 4 + quad) ^ c7) << 3)];
#pragma unroll
      for (int mi = 0; mi < 4; mi++)
#pragma unroll
        for (int ni = 0; ni < 4; ni++)
          acc[mi][ni] = MFMA16(af[mi], bfr[ni], acc[mi][ni]);
    }
  }
#pragma unroll
  for (int mi = 0; mi < 4; mi++) {
#pragma unroll
    for (int ni = 0; ni < 4; ni++) {
      const int e = n0 + wn * 64 + ni * 16 + col;
#pragma unroll
      for (int r = 0; r < 4; r++) {
        const int m = m0 + wm * 64 + mi * 16 + quad * 4 + r;
        const int bb = m >> 11, t = m & 2047;
        if (e < 1024) {
          qb[(((size_t)bb * 16 + (e >> 6)) * 2048 + t) * 64 + (e & 63)] =
              (bf16)(acc[mi][ni][r] * QSCALE);
        } else if (e < 1280) {
          const int f = e - 1024;
          kb[(((size_t)bb * 4 + (f >> 6)) * 2048 + t) * 64 + (f & 63)] =
              (bf16)acc[mi][ni][r];
        } else {
          const int f = e - 1280;
          vb[(((size_t)bb * 4 + (f >> 6)) * 2048 + t) * 64 + (f & 63)] =
              (bf16)acc[mi][ni][r];
        }
      }
    }
  }
}

// ------------------------------------------------------------------
// GEMM2: out[m,e] = sum_c AO[m,c] * Wproj[e,c] + bias[e]  (fp32 out)
// ------------------------------------------------------------------
__global__ __launch_bounds__(256, 2)
void gemm_proj(const bf16* __restrict__ A, const bf16* __restrict__ B,
               const float* __restrict__ bias, float* __restrict__ out) {
  constexpr int K = 1024;
  __shared__ bf16 sA[128 * 64];
  __shared__ bf16 sB[128 * 64];
  const int tid = threadIdx.x;
  const int lane = tid & 63, wid = tid >> 6;
  const int col = lane & 15, quad = lane >> 4;
  const int wm = wid >> 1, wn = wid & 1;
  const int m0 = blockIdx.y * 128, n0 = blockIdx.x * 128;
  const int c7 = col & 7;

  f32x4 acc[4][4];
  const f32x4 z = {0.f, 0.f, 0.f, 0.f};
#pragma unroll
  for (int mi = 0; mi < 4; mi++)
#pragma unroll
    for (int ni = 0; ni < 4; ni++) acc[mi][ni] = z;

  for (int k0 = 0; k0 < K; k0 += 64) {
    __syncthreads();
#pragma unroll
    for (int c = 0; c < 4; ++c) {
      const int idx = c * 256 + tid;
      const int row = idx >> 3, kc = idx & 7;
      const int gkc = kc ^ (row & 7);
      async16(&A[(size_t)(m0 + row) * K + k0 + gkc * 8], &sA[idx * 8]);
      async16(&B[(size_t)(n0 + row) * K + k0 + gkc * 8], &sB[idx * 8]);
    }
    __syncthreads();
#pragma unroll
    for (int ks = 0; ks < 2; ++ks) {
      bf16x8 af[4], bfr[4];
#pragma unroll
      for (int i = 0; i < 4; i++)
        af[i] = *(const bf16x8*)&sA[(wm * 64 + i * 16 + col) * 64 +
                                    (((ks * 4 + quad) ^ c7) << 3)];
#pragma unroll
      for (int i = 0; i < 4; i++)
        bfr[i] = *(const bf16x8*)&sB[(wn * 64 + i * 16 + col) * 64 +
                                     (((ks * 4 + quad) ^ c7) << 3)];
#pragma unroll
      for (int mi = 0; mi < 4; mi++)
#pragma unroll
        for (int ni = 0; ni < 4; ni++)
          acc[mi][ni] = MFMA16(af[mi], bfr[ni], acc[mi][ni]);
    }
  }
#pragma unroll
  for (int mi = 0; mi < 4; mi++) {
#pragma unroll
    for (int ni = 0; ni < 4; ni++) {
      const int e = n0 + wn * 64 + ni * 16 + col;
      const float be = bias[e];
#pragma unroll
      for (int r = 0; r < 4; r++) {
        const int m = m0 + wm * 64 + mi * 16 + quad * 4 + r;
        out[(size_t)m * 1024 + e] = acc[mi][ni][r] + be;
      }
    }
  }
}

// ------------------------------------------------------------------
// Flash attention, ALiBi bias, fixed-max softmax, transposed dataflow.
// Q pre-scaled by QSCALE (exp2 domain).  Row sums via an all-ones
// MFMA B-operand (every lane gets its row sum in C-layout).  K/V
// prefetched one chunk ahead, issued after the 2nd barrier so no
// barrier ever drains an unfinished load.
// ------------------------------------------------------------------
__global__ __launch_bounds__(256, 2)
void attn_alibi(const bf16* __restrict__ qb, const bf16* __restrict__ kb,
                const bf16* __restrict__ vb, bf16* __restrict__ ob) {
  __shared__ bf16 sK[64 * 64];      // [kv][d], xor-swizzled stride 64
  __shared__ bf16 sVt[64 * 72];     // [d][kv], stride 72, kv-block xor-swizzle
  __shared__ bf16 sPt[4][64 * 64];  // per wave: [q][kv], xor-swizzled stride 64
  const int tid = threadIdx.x;
  const int lane = tid & 63, wid = tid >> 6;
  const int col = lane & 15, quad = lane >> 4;
  const int c7 = col & 7;
  const int bh = blockIdx.y;
  const int b = bh >> 4, h = bh & 15, kvh = h & 3;
  const int qbase = __builtin_amdgcn_readfirstlane(blockIdx.x * 256 + wid * 64);

  const bf16* qptr = qb + ((size_t)(b * 16 + h) * 2048 + qbase) * 64;
  const bf16* kptr = kb + ((size_t)(b * 4 + kvh) * 2048) * 64;
  const bf16* vptr = vb + ((size_t)(b * 4 + kvh) * 2048) * 64;

  // Q resident as B-operand frags: B[n=q (col)][k=d]
  bf16x8 bq[4][2];
#pragma unroll
  for (int ni = 0; ni < 4; ni++)
#pragma unroll
    for (int ks = 0; ks < 2; ks++)
      bq[ni][ks] = *(const bf16x8*)&qptr[(ni * 16 + col) * 64 + ks * 32 + quad * 8];

  // all-ones B-frag for MFMA row sums
  bf16x8 bones;
#pragma unroll
  for (int j = 0; j < 8; j++) bones[j] = (bf16)1.0f;

  f32x4 O[4][4];     // O[q-tile][d-tile], C-layout rows=q
  f32x4 Osum[4];     // row sums of P per q-tile (same C-layout rows)
  const f32x4 z = {0.f, 0.f, 0.f, 0.f};
#pragma unroll
  for (int mi = 0; mi < 4; mi++) {
    Osum[mi] = z;
#pragma unroll
    for (int nd = 0; nd < 4; nd++) O[mi][nd] = z;
  }

  const float cb = exp2f(-0.5f * (float)(h + 1)) * QSCALE;  // bias slope, exp2 domain
  const int qoff = quad * 4 - col;

  // staging coords: K rows (tid>>3, +32); V row pair (2*(tid>>3), +1)
  const int rk0 = tid >> 3, rk1 = 32 + rk0, kc = tid & 7;
  const int rv = rk0 * 2;
  const int blkv = rv >> 3, rlv = rv & 7;
  const int kx = (kc ^ (rk0 & 7)) << 3;  // rk1&7 == rk0&7

  // prefetch chunk 0
  bf16x8 kr0 = *(const bf16x8*)&kptr[(size_t)rk0 * 64 + kc * 8];
  bf16x8 kr1 = *(const bf16x8*)&kptr[(size_t)rk1 * 64 + kc * 8];
  bf16x8 vr0 = *(const bf16x8*)&vptr[(size_t)rv * 64 + kc * 8];
  bf16x8 vr1 = *(const bf16x8*)&vptr[(size_t)(rv + 1) * 64 + kc * 8];

  for (int c0 = 0; c0 < 2048; c0 += 64) {
    __syncthreads();  // all waves done reading previous chunk's sK/sVt
    *(bf16x8*)&sK[rk0 * 64 + kx] = kr0;
    *(bf16x8*)&sK[rk1 * 64 + kx] = kr1;
#pragma unroll
    for (int j = 0; j < 8; j++) {
      bf16x2 pr;
      pr.x = vr0[j];
      pr.y = vr1[j];
      *(bf16x2*)&sVt[(kc * 8 + j) * 72 + ((blkv ^ kc) << 3) + rlv] = pr;
    }
    __syncthreads();  // staging visible; nothing in flight to drain

    // issue next chunk's loads — whole compute phase covers their latency
    {
      const int cn = (c0 + 64 < 2048) ? c0 + 64 : 0;
      kr0 = *(const bf16x8*)&kptr[(size_t)(cn + rk0) * 64 + kc * 8];
      kr1 = *(const bf16x8*)&kptr[(size_t)(cn + rk1) * 64 + kc * 8];
      vr0 = *(const bf16x8*)&vptr[(size_t)(cn + rv) * 64 + kc * 8];
      vr1 = *(const bf16x8*)&vptr[(size_t)(cn + rv + 1) * 64 + kc * 8];
    }

    // S^T = K Q^T : rows=kv, cols=q  (Q pre-scaled: S is in exp2 domain)
    f32x4 S[4][4];
#pragma unroll
    for (int mi = 0; mi < 4; mi++)
#pragma unroll
      for (int ni = 0; ni < 4; ni++) S[mi][ni] = z;
#pragma unroll
    for (int ks = 0; ks < 2; ks++) {
      bf16x8 ak[4];
#pragma unroll
      for (int mi = 0; mi < 4; mi++)
        ak[mi] = *(const bf16x8*)&sK[(mi * 16 + col) * 64 +
                                     (((ks * 4 + quad) ^ c7) << 3)];
#pragma unroll
      for (int mi = 0; mi < 4; mi++)
#pragma unroll
        for (int ni = 0; ni < 4; ni++)
          S[mi][ni] = MFMA16(ak[mi], bq[ni][ks], S[mi][ni]);
    }

    // bias + exp2 (fixed max M=0), pack P into sPt (swizzled)
    bf16* sp = sPt[wid];
#pragma unroll
    for (int ni = 0; ni < 4; ni++) {
#pragma unroll
      for (int mi = 0; mi < 4; mi++) {
        const int U = c0 + mi * 16 - qbase - ni * 16;  // wave-uniform
        f32x4 p;
        if (U <= -15) {
          const float bb = cb * (float)(U + qoff);
#pragma unroll
          for (int r = 0; r < 4; r++)
            p[r] = __builtin_amdgcn_exp2f(S[mi][ni][r] + (bb + cb * (float)r));
        } else if (U >= 16) {
#pragma unroll
          for (int r = 0; r < 4; r++)
            p[r] = __builtin_amdgcn_exp2f(S[mi][ni][r]);
        } else {
          const float relf = (float)(U + qoff);
#pragma unroll
          for (int r = 0; r < 4; r++) {
            const float rr = relf + (float)r;
            const float bb = (rr <= 0.f) ? cb * rr : 0.f;
            p[r] = __builtin_amdgcn_exp2f(S[mi][ni][r] + bb);
          }
        }
        bf16x4 w;
#pragma unroll
        for (int r = 0; r < 4; r++) w[r] = (bf16)p[r];
        *(bf16x4*)&sp[(ni * 16 + col) * 64 +
                      (((2 * mi + (quad >> 1)) ^ c7) << 3) + ((quad & 1) << 2)] = w;
      }
    }

    // O += P V ; Osum += P · 1   (same-wave sPt dep handled by lgkmcnt)
#pragma unroll
    for (int ks = 0; ks < 2; ks++) {
      bf16x8 ap[4], bv[4];
#pragma unroll
      for (int mi = 0; mi < 4; mi++)
        ap[mi] = *(const bf16x8*)&sp[(mi * 16 + col) * 64 +
                                     (((ks * 4 + quad) ^ c7) << 3)];
#pragma unroll
      for (int nd = 0; nd < 4; nd++) {
        const int d = nd * 16 + col;
        bv[nd] = *(const bf16x8*)&sVt[d * 72 + (((ks * 4 + quad) ^ (d >> 3)) << 3)];
      }
#pragma unroll
      for (int mi = 0; mi < 4; mi++) {
#pragma unroll
        for (int nd = 0; nd < 4; nd++)
          O[mi][nd] = MFMA16(ap[mi], bv[nd], O[mi][nd]);
        Osum[mi] = MFMA16(ap[mi], bones, Osum[mi]);
      }
    }
  }

  // epilogue: every lane holds its row sum in Osum[mi][r]
#pragma unroll
  for (int mi = 0; mi < 4; mi++) {
#pragma unroll
    for (int r = 0; r < 4; r++) {
      const float inv = 1.0f / Osum[mi][r];
      const int t = qbase + mi * 16 + quad * 4 + r;
#pragma unroll
      for (int nd = 0; nd < 4; nd++) {
        ob[((size_t)b * 2048 + t) * 1024 + h * 64 + nd * 16 + col] =
            (bf16)(O[mi][nd][r] * inv);
      }
    }
  }
}

// ------------------------------------------------------------------
extern "C" void kernel_launch(void* const* d_in, const int* in_sizes, int n_in,
                              void* d_out, int out_size, void* d_ws, size_t ws_size,
                              hipStream_t stream) {
  const float* x     = (const float*)d_in[0];
  const float* Wq    = (const float*)d_in[1];
  const float* Wkv   = (const float*)d_in[2];
  const float* Wproj = (const float*)d_in[3];
  const float* bproj = (const float*)d_in[4];
  float* out = (float*)d_out;

  bf16* xb  = (bf16*)d_ws;            // 8192*1024
  bf16* w1b = xb  + 8388608;          // 1536*1024
  bf16* wpb = w1b + 1572864;          // 1024*1024
  bf16* qb  = wpb + 1048576;          // [4,16,2048,64]
  bf16* kb  = qb  + 8388608;          // [4,4,2048,64]
  bf16* vb  = kb  + 2097152;          // [4,4,2048,64]
  bf16* aob = vb  + 2097152;          // [4,2048,1024]

  cast_f32_to_bf16<<<8192, 256, 0, stream>>>(x, xb, 2097152);
  cast_f32_to_bf16<<<1024, 256, 0, stream>>>(Wq, w1b, 262144);
  cast_f32_to_bf16<<<512, 256, 0, stream>>>(Wkv, w1b + 1048576, 131072);
  cast_f32_to_bf16<<<1024, 256, 0, stream>>>(Wproj, wpb, 262144);

  gemm_qkv<<<dim3(12, 64), 256, 0, stream>>>(xb, w1b, qb, kb, vb);
  attn_alibi<<<dim3(8, 64), 256, 0, stream>>>(qb, kb, vb, aob);
  gemm_proj<<<dim3(8, 64), 256, 0, stream>>>(aob, wpb, bproj, out);
}

// Round 5
// 240.426 us; speedup vs baseline: 1.1678x; 1.0337x over previous
//
#include <hip/hip_runtime.h>
#include <hip/hip_bf16.h>
#include <cstdint>

typedef __bf16 bf16;
typedef bf16 bf16x2 __attribute__((ext_vector_type(2)));
typedef bf16 bf16x4 __attribute__((ext_vector_type(4)));
typedef bf16 bf16x8 __attribute__((ext_vector_type(8)));
typedef float f32x4 __attribute__((ext_vector_type(4)));

#define MFMA16(a, b, c) __builtin_amdgcn_mfma_f32_16x16x32_bf16((a), (b), (c), 0, 0, 0)

// 0.125 * log2(e): folded into Q at the QKV-GEMM epilogue
#define QSCALE 0.18033688011112042f

// async global->LDS DMA, 16B/lane. LDS dest must be wave-uniform base + lane*16.
__device__ inline void async16(const bf16* g, bf16* l) {
  __builtin_amdgcn_global_load_lds(
      (const __attribute__((address_space(1))) void*)g,
      (__attribute__((address_space(3))) void*)l, 16, 0, 0);
}

// ------------------------------------------------------------------
// fused cast fp32 -> bf16 for all four inputs (one launch)
// float4-index ranges: x[0,2097152) Wq[..2359296) Wkv[..2490368) Wproj[..2752512)
// ------------------------------------------------------------------
__global__ void cast_all(const float* __restrict__ x, const float* __restrict__ wq,
                         const float* __restrict__ wkv, const float* __restrict__ wp,
                         bf16* __restrict__ xb, bf16* __restrict__ w1b,
                         bf16* __restrict__ wpb) {
  const int i = blockIdx.x * blockDim.x + threadIdx.x;
  const float4* src;
  bf16x4* dst;
  int idx;
  if (i < 2097152) {
    src = (const float4*)x; dst = (bf16x4*)xb; idx = i;
  } else if (i < 2359296) {
    src = (const float4*)wq; dst = (bf16x4*)w1b; idx = i - 2097152;
  } else if (i < 2490368) {
    src = (const float4*)wkv; dst = (bf16x4*)(w1b + 1048576); idx = i - 2359296;
  } else {
    src = (const float4*)wp; dst = (bf16x4*)wpb; idx = i - 2490368;
  }
  const float4 v = src[idx];
  bf16x4 o;
  o.x = (bf16)v.x; o.y = (bf16)v.y; o.z = (bf16)v.z; o.w = (bf16)v.w;
  dst[idx] = o;
}

// ------------------------------------------------------------------
// GEMM1: C[m,e] = sum_c x[m,c] * W1[e,c]   (M=8192, N=1536, K=1024)
// global_load_lds staging, xor-swizzled unpadded LDS (stride 64).
// Q outputs pre-scaled by QSCALE for the attention exp2 domain.
// ------------------------------------------------------------------
__global__ __launch_bounds__(256, 2)
void gemm_qkv(const bf16* __restrict__ A, const bf16* __restrict__ B,
              bf16* __restrict__ qb, bf16* __restrict__ kb, bf16* __restrict__ vb) {
  constexpr int K = 1024;
  __shared__ bf16 sA[128 * 64];
  __shared__ bf16 sB[128 * 64];
  const int tid = threadIdx.x;
  const int lane = tid & 63, wid = tid >> 6;
  const int col = lane & 15, quad = lane >> 4;
  const int wm = wid >> 1, wn = wid & 1;
  const int m0 = blockIdx.y * 128, n0 = blockIdx.x * 128;
  const int c7 = col & 7;

  f32x4 acc[4][4];
  const f32x4 z = {0.f, 0.f, 0.f, 0.f};
#pragma unroll
  for (int mi = 0; mi < 4; mi++)
#pragma unroll
    for (int ni = 0; ni < 4; ni++) acc[mi][ni] = z;

  for (int k0 = 0; k0 < K; k0 += 64) {
    __syncthreads();
#pragma unroll
    for (int c = 0; c < 4; ++c) {
      const int idx = c * 256 + tid;
      const int row = idx >> 3, kc = idx & 7;
      const int gkc = kc ^ (row & 7);
      async16(&A[(size_t)(m0 + row) * K + k0 + gkc * 8], &sA[idx * 8]);
      async16(&B[(size_t)(n0 + row) * K + k0 + gkc * 8], &sB[idx * 8]);
    }
    __syncthreads();  // vmcnt(0) drain: DMA complete
#pragma unroll
    for (int ks = 0; ks < 2; ++ks) {
      bf16x8 af[4], bfr[4];
#pragma unroll
      for (int i = 0; i < 4; i++)
        af[i] = *(const bf16x8*)&sA[(wm * 64 + i * 16 + col) * 64 +
                                    (((ks * 4 + quad) ^ c7) << 3)];
#pragma unroll
      for (int i = 0; i < 4; i++)
        bfr[i] = *(const bf16x8*)&sB[(wn * 64 + i * 16 + col) * 64 +
                                     (((ks * 4 + quad) ^ c7) << 3)];
#pragma unroll
      for (int mi = 0; mi < 4; mi++)
#pragma unroll
        for (int ni = 0; ni < 4; ni++)
          acc[mi][ni] = MFMA16(af[mi], bfr[ni], acc[mi][ni]);
    }
  }
#pragma unroll
  for (int mi = 0; mi < 4; mi++) {
#pragma unroll
    for (int ni = 0; ni < 4; ni++) {
      const int e = n0 + wn * 64 + ni * 16 + col;
#pragma unroll
      for (int r = 0; r < 4; r++) {
        const int m = m0 + wm * 64 + mi * 16 + quad * 4 + r;
        const int bb = m >> 11, t = m & 2047;
        if (e < 1024) {
          qb[(((size_t)bb * 16 + (e >> 6)) * 2048 + t) * 64 + (e & 63)] =
              (bf16)(acc[mi][ni][r] * QSCALE);
        } else if (e < 1280) {
          const int f = e - 1024;
          kb[(((size_t)bb * 4 + (f >> 6)) * 2048 + t) * 64 + (f & 63)] =
              (bf16)acc[mi][ni][r];
        } else {
          const int f = e - 1280;
          vb[(((size_t)bb * 4 + (f >> 6)) * 2048 + t) * 64 + (f & 63)] =
              (bf16)acc[mi][ni][r];
        }
      }
    }
  }
}

// ------------------------------------------------------------------
// GEMM2: out[m,e] = sum_c AO[m,c] * Wproj[e,c] + bias[e]  (fp32 out)
// ------------------------------------------------------------------
__global__ __launch_bounds__(256, 2)
void gemm_proj(const bf16* __restrict__ A, const bf16* __restrict__ B,
               const float* __restrict__ bias, float* __restrict__ out) {
  constexpr int K = 1024;
  __shared__ bf16 sA[128 * 64];
  __shared__ bf16 sB[128 * 64];
  const int tid = threadIdx.x;
  const int lane = tid & 63, wid = tid >> 6;
  const int col = lane & 15, quad = lane >> 4;
  const int wm = wid >> 1, wn = wid & 1;
  const int m0 = blockIdx.y * 128, n0 = blockIdx.x * 128;
  const int c7 = col & 7;

  f32x4 acc[4][4];
  const f32x4 z = {0.f, 0.f, 0.f, 0.f};
#pragma unroll
  for (int mi = 0; mi < 4; mi++)
#pragma unroll
    for (int ni = 0; ni < 4; ni++) acc[mi][ni] = z;

  for (int k0 = 0; k0 < K; k0 += 64) {
    __syncthreads();
#pragma unroll
    for (int c = 0; c < 4; ++c) {
      const int idx = c * 256 + tid;
      const int row = idx >> 3, kc = idx & 7;
      const int gkc = kc ^ (row & 7);
      async16(&A[(size_t)(m0 + row) * K + k0 + gkc * 8], &sA[idx * 8]);
      async16(&B[(size_t)(n0 + row) * K + k0 + gkc * 8], &sB[idx * 8]);
    }
    __syncthreads();
#pragma unroll
    for (int ks = 0; ks < 2; ++ks) {
      bf16x8 af[4], bfr[4];
#pragma unroll
      for (int i = 0; i < 4; i++)
        af[i] = *(const bf16x8*)&sA[(wm * 64 + i * 16 + col) * 64 +
                                    (((ks * 4 + quad) ^ c7) << 3)];
#pragma unroll
      for (int i = 0; i < 4; i++)
        bfr[i] = *(const bf16x8*)&sB[(wn * 64 + i * 16 + col) * 64 +
                                     (((ks * 4 + quad) ^ c7) << 3)];
#pragma unroll
      for (int mi = 0; mi < 4; mi++)
#pragma unroll
        for (int ni = 0; ni < 4; ni++)
          acc[mi][ni] = MFMA16(af[mi], bfr[ni], acc[mi][ni]);
    }
  }
#pragma unroll
  for (int mi = 0; mi < 4; mi++) {
#pragma unroll
    for (int ni = 0; ni < 4; ni++) {
      const int e = n0 + wn * 64 + ni * 16 + col;
      const float be = bias[e];
#pragma unroll
      for (int r = 0; r < 4; r++) {
        const int m = m0 + wm * 64 + mi * 16 + quad * 4 + r;
        out[(size_t)m * 1024 + e] = acc[mi][ni][r] + be;
      }
    }
  }
}

// ------------------------------------------------------------------
// Flash attention, ALiBi bias, fixed-max softmax, transposed dataflow.
// K/V double-buffered in LDS -> exactly ONE __syncthreads per chunk.
// Row sums via all-ones MFMA B-operand.  Q pre-scaled (exp2 domain).
// ------------------------------------------------------------------
__global__ __launch_bounds__(256, 2)
void attn_alibi(const bf16* __restrict__ qb, const bf16* __restrict__ kb,
                const bf16* __restrict__ vb, bf16* __restrict__ ob) {
  __shared__ bf16 sK[2][64 * 64];   // [buf][kv][d], xor-swizzled stride 64
  __shared__ bf16 sVt[2][64 * 72];  // [buf][d][kv], stride 72, kv-block xor-swizzle
  __shared__ bf16 sPt[4][64 * 64];  // per wave: [q][kv], xor-swizzled stride 64
  const int tid = threadIdx.x;
  const int lane = tid & 63, wid = tid >> 6;
  const int col = lane & 15, quad = lane >> 4;
  const int c7 = col & 7;
  const int bh = blockIdx.y;
  const int b = bh >> 4, h = bh & 15, kvh = h & 3;
  const int qbase = __builtin_amdgcn_readfirstlane(blockIdx.x * 256 + wid * 64);

  const bf16* qptr = qb + ((size_t)(b * 16 + h) * 2048 + qbase) * 64;
  const bf16* kptr = kb + ((size_t)(b * 4 + kvh) * 2048) * 64;
  const bf16* vptr = vb + ((size_t)(b * 4 + kvh) * 2048) * 64;

  // Q resident as B-operand frags: B[n=q (col)][k=d]
  bf16x8 bq[4][2];
#pragma unroll
  for (int ni = 0; ni < 4; ni++)
#pragma unroll
    for (int ks = 0; ks < 2; ks++)
      bq[ni][ks] = *(const bf16x8*)&qptr[(ni * 16 + col) * 64 + ks * 32 + quad * 8];

  // all-ones B-frag for MFMA row sums
  bf16x8 bones;
#pragma unroll
  for (int j = 0; j < 8; j++) bones[j] = (bf16)1.0f;

  f32x4 O[4][4];  // O[q-tile][d-tile], C-layout rows=q
  f32x4 Osum[4];  // row sums of P per q-tile
  const f32x4 z = {0.f, 0.f, 0.f, 0.f};
#pragma unroll
  for (int mi = 0; mi < 4; mi++) {
    Osum[mi] = z;
#pragma unroll
    for (int nd = 0; nd < 4; nd++) O[mi][nd] = z;
  }

  const float cb = exp2f(-0.5f * (float)(h + 1)) * QSCALE;  // bias slope, exp2 domain
  const int qoff = quad * 4 - col;

  // staging coords: K rows (tid>>3, +32); V row pair (2*(tid>>3), +1)
  const int rk0 = tid >> 3, rk1 = 32 + rk0, kc = tid & 7;
  const int rv = rk0 * 2;
  const int blkv = rv >> 3, rlv = rv & 7;
  const int kx = (kc ^ (rk0 & 7)) << 3;  // rk1&7 == rk0&7

  // prefetch chunk 0
  bf16x8 kr0 = *(const bf16x8*)&kptr[(size_t)rk0 * 64 + kc * 8];
  bf16x8 kr1 = *(const bf16x8*)&kptr[(size_t)rk1 * 64 + kc * 8];
  bf16x8 vr0 = *(const bf16x8*)&vptr[(size_t)rv * 64 + kc * 8];
  bf16x8 vr1 = *(const bf16x8*)&vptr[(size_t)(rv + 1) * 64 + kc * 8];

  int bufi = 0;
  for (int c0 = 0; c0 < 2048; c0 += 64, bufi ^= 1) {
    // commit prefetched regs to current buffer
    bf16* skw = sK[bufi];
    bf16* svw = sVt[bufi];
    *(bf16x8*)&skw[rk0 * 64 + kx] = kr0;
    *(bf16x8*)&skw[rk1 * 64 + kx] = kr1;
#pragma unroll
    for (int j = 0; j < 8; j++) {
      bf16x2 pr;
      pr.x = vr0[j];
      pr.y = vr1[j];
      *(bf16x2*)&svw[(kc * 8 + j) * 72 + ((blkv ^ kc) << 3) + rlv] = pr;
    }
    __syncthreads();  // single barrier: buffer visible; other buffer free

    // issue next chunk's loads — whole compute phase covers their latency
    {
      const int cn = (c0 + 64 < 2048) ? c0 + 64 : 0;
      kr0 = *(const bf16x8*)&kptr[(size_t)(cn + rk0) * 64 + kc * 8];
      kr1 = *(const bf16x8*)&kptr[(size_t)(cn + rk1) * 64 + kc * 8];
      vr0 = *(const bf16x8*)&vptr[(size_t)(cn + rv) * 64 + kc * 8];
      vr1 = *(const bf16x8*)&vptr[(size_t)(cn + rv + 1) * 64 + kc * 8];
    }

    // S^T = K Q^T : rows=kv, cols=q  (Q pre-scaled: S is in exp2 domain)
    f32x4 S[4][4];
#pragma unroll
    for (int mi = 0; mi < 4; mi++)
#pragma unroll
      for (int ni = 0; ni < 4; ni++) S[mi][ni] = z;
#pragma unroll
    for (int ks = 0; ks < 2; ks++) {
      bf16x8 ak[4];
#pragma unroll
      for (int mi = 0; mi < 4; mi++)
        ak[mi] = *(const bf16x8*)&skw[(mi * 16 + col) * 64 +
                                      (((ks * 4 + quad) ^ c7) << 3)];
#pragma unroll
      for (int mi = 0; mi < 4; mi++)
#pragma unroll
        for (int ni = 0; ni < 4; ni++)
          S[mi][ni] = MFMA16(ak[mi], bq[ni][ks], S[mi][ni]);
    }

    // bias + exp2 (fixed max M=0), pack P into sPt (swizzled)
    bf16* sp = sPt[wid];
#pragma unroll
    for (int ni = 0; ni < 4; ni++) {
#pragma unroll
      for (int mi = 0; mi < 4; mi++) {
        const int U = c0 + mi * 16 - qbase - ni * 16;  // wave-uniform
        f32x4 p;
        if (U <= -15) {
          const float bb = cb * (float)(U + qoff);
#pragma unroll
          for (int r = 0; r < 4; r++)
            p[r] = __builtin_amdgcn_exp2f(S[mi][ni][r] + (bb + cb * (float)r));
        } else if (U >= 16) {
#pragma unroll
          for (int r = 0; r < 4; r++)
            p[r] = __builtin_amdgcn_exp2f(S[mi][ni][r]);
        } else {
          const float relf = (float)(U + qoff);
#pragma unroll
          for (int r = 0; r < 4; r++) {
            const float rr = relf + (float)r;
            const float bb = (rr <= 0.f) ? cb * rr : 0.f;
            p[r] = __builtin_amdgcn_exp2f(S[mi][ni][r] + bb);
          }
        }
        bf16x4 w;
#pragma unroll
        for (int r = 0; r < 4; r++) w[r] = (bf16)p[r];
        *(bf16x4*)&sp[(ni * 16 + col) * 64 +
                      (((2 * mi + (quad >> 1)) ^ c7) << 3) + ((quad & 1) << 2)] = w;
      }
    }

    // O += P V ; Osum += P · 1   (same-wave sPt dep handled by lgkmcnt)
#pragma unroll
    for (int ks = 0; ks < 2; ks++) {
      bf16x8 ap[4], bv[4];
#pragma unroll
      for (int mi = 0; mi < 4; mi++)
        ap[mi] = *(const bf16x8*)&sp[(mi * 16 + col) * 64 +
                                     (((ks * 4 + quad) ^ c7) << 3)];
#pragma unroll
      for (int nd = 0; nd < 4; nd++) {
        const int d = nd * 16 + col;
        bv[nd] = *(const bf16x8*)&svw[d * 72 + (((ks * 4 + quad) ^ (d >> 3)) << 3)];
      }
#pragma unroll
      for (int mi = 0; mi < 4; mi++) {
#pragma unroll
        for (int nd = 0; nd < 4; nd++)
          O[mi][nd] = MFMA16(ap[mi], bv[nd], O[mi][nd]);
        Osum[mi] = MFMA16(ap[mi], bones, Osum[mi]);
      }
    }
  }

  // epilogue: every lane holds its row sum in Osum[mi][r]
#pragma unroll
  for (int mi = 0; mi < 4; mi++) {
#pragma unroll
    for (int r = 0; r < 4; r++) {
      const float inv = 1.0f / Osum[mi][r];
      const int t = qbase + mi * 16 + quad * 4 + r;
#pragma unroll
      for (int nd = 0; nd < 4; nd++) {
        ob[((size_t)b * 2048 + t) * 1024 + h * 64 + nd * 16 + col] =
            (bf16)(O[mi][nd][r] * inv);
      }
    }
  }
}

// ------------------------------------------------------------------
extern "C" void kernel_launch(void* const* d_in, const int* in_sizes, int n_in,
                              void* d_out, int out_size, void* d_ws, size_t ws_size,
                              hipStream_t stream) {
  const float* x     = (const float*)d_in[0];
  const float* Wq    = (const float*)d_in[1];
  const float* Wkv   = (const float*)d_in[2];
  const float* Wproj = (const float*)d_in[3];
  const float* bproj = (const float*)d_in[4];
  float* out = (float*)d_out;

  bf16* xb  = (bf16*)d_ws;            // 8192*1024
  bf16* w1b = xb  + 8388608;          // 1536*1024
  bf16* wpb = w1b + 1572864;          // 1024*1024
  bf16* qb  = wpb + 1048576;          // [4,16,2048,64]
  bf16* kb  = qb  + 8388608;          // [4,4,2048,64]
  bf16* vb  = kb  + 2097152;          // [4,4,2048,64]
  bf16* aob = vb  + 2097152;          // [4,2048,1024]

  cast_all<<<10752, 256, 0, stream>>>(x, Wq, Wkv, Wproj, xb, w1b, wpb);
  gemm_qkv<<<dim3(12, 64), 256, 0, stream>>>(xb, w1b, qb, kb, vb);
  attn_alibi<<<dim3(8, 64), 256, 0, stream>>>(qb, kb, vb, aob);
  gemm_proj<<<dim3(8, 64), 256, 0, stream>>>(aob, wpb, bproj, out);
}